// Round 8
// baseline (857.954 us; speedup 1.0000x reference)
//
#include <hip/hip_runtime.h>

#define BT (256*512)   // 131072 positions
#define HID 128
#define EMB 64
#define CH 32          // scan chunk: steps staged per LDS refill

typedef unsigned short bf16_t;

__device__ inline float bf2f(bf16_t u) {
    union { unsigned int i; float f; } v; v.i = ((unsigned int)u) << 16; return v.f;
}
__device__ inline bf16_t f2bf(float f) {
    union { float f; unsigned int i; } v; v.f = f;
    unsigned int x = v.i;
    return (bf16_t)((x + 0x7fffu + ((x >> 16) & 1u)) >> 16);  // RNE
}
// tanh(x) = 1 - 2/(exp(2x)+1)  — stable at both infinities, ~1e-6 abs error
__device__ inline float fast_tanh(float x) {
    float e = __expf(2.f * x);
    return 1.f - __fdividef(2.f, e + 1.f);
}

// pin a float4 in VGPRs (compiler cannot rematerialize past this)
#define OPQ(v) asm volatile("" : "+v"(v.x), "+v"(v.y), "+v"(v.z), "+v"(v.w))

#define W16LOAD \
    float4 w0=wr[0],w1=wr[1],w2=wr[2],w3=wr[3],w4=wr[4],w5=wr[5],w6=wr[6],w7=wr[7], \
           w8=wr[8],w9=wr[9],w10=wr[10],w11=wr[11],w12=wr[12],w13=wr[13],w14=wr[14],w15=wr[15];
#define W16PIN \
    OPQ(w0);OPQ(w1);OPQ(w2);OPQ(w3);OPQ(w4);OPQ(w5);OPQ(w6);OPQ(w7); \
    OPQ(w8);OPQ(w9);OPQ(w10);OPQ(w11);OPQ(w12);OPQ(w13);OPQ(w14);OPQ(w15);
#define W32LOAD W16LOAD \
    float4 w16=wr[16],w17=wr[17],w18=wr[18],w19=wr[19],w20=wr[20],w21=wr[21],w22=wr[22],w23=wr[23], \
           w24=wr[24],w25=wr[25],w26=wr[26],w27=wr[27],w28=wr[28],w29=wr[29],w30=wr[30],w31=wr[31];
#define W32PIN W16PIN \
    OPQ(w16);OPQ(w17);OPQ(w18);OPQ(w19);OPQ(w20);OPQ(w21);OPQ(w22);OPQ(w23); \
    OPQ(w24);OPQ(w25);OPQ(w26);OPQ(w27);OPQ(w28);OPQ(w29);OPQ(w30);OPQ(w31);
#define ACC4(n) { float4 hv = hp[n]; \
    a0 = fmaf(hv.x, w##n.x, a0); a1 = fmaf(hv.y, w##n.y, a1); \
    a2 = fmaf(hv.z, w##n.z, a2); a3 = fmaf(hv.w, w##n.w, a3); }
#define ACC16 ACC4(0)ACC4(1)ACC4(2)ACC4(3)ACC4(4)ACC4(5)ACC4(6)ACC4(7) \
              ACC4(8)ACC4(9)ACC4(10)ACC4(11)ACC4(12)ACC4(13)ACC4(14)ACC4(15)
#define ACC32 ACC16 \
              ACC4(16)ACC4(17)ACC4(18)ACC4(19)ACC4(20)ACC4(21)ACC4(22)ACC4(23) \
              ACC4(24)ACC4(25)ACC4(26)ACC4(27)ACC4(28)ACC4(29)ACC4(30)ACC4(31)

// ---------------- kernel 1: embedding gather + layer-1 input GEMM (+both biases)
__global__ __launch_bounds__(128)
__attribute__((amdgpu_waves_per_eu(1, 4)))
void k_embed_pre1(
    const int* __restrict__ x, const float* __restrict__ emb,
    const float* __restrict__ Wih1, const float* __restrict__ bih1,
    const float* __restrict__ bhh1, float* __restrict__ pre1)
{
    __shared__ __align__(16) float se[8 * EMB];
    __shared__ int stok[8];
    const int base = blockIdx.x * 8;
    const int i = threadIdx.x;
    if (i < 8) stok[i] = x[base + i];
    __syncthreads();
    {   // gather 8 emb rows (16 float4 each) — one float4 per thread
        int p = i >> 4, c = i & 15;
        ((float4*)se)[i] = ((const float4*)(emb + (size_t)stok[p] * EMB))[c];
    }
    __syncthreads();
    const float4* wr = reinterpret_cast<const float4*>(Wih1 + i * EMB);
    W16LOAD; W16PIN;
    const float bias = bih1[i] + bhh1[i];
    float* outp = pre1 + (size_t)base * HID + i;
#pragma unroll
    for (int p = 0; p < 8; ++p) {
        const float4* hp = reinterpret_cast<const float4*>(se + p * EMB);
        float a0 = 0, a1 = 0, a2 = 0, a3 = 0;
        ACC16;
        outp[p * HID] = bias + ((a0 + a1) + (a2 + a3));
    }
}

// ---------------- kernel 2: layer-1 recurrence. one block per batch row.
// 128 threads (2 waves), thread i owns FULL Whh row i (32 pinned float4 =
// 128 VGPRs; waves_per_eu(1,1) gives the 512-reg budget — R6-proven).
// No K-split -> no partial-sum LDS round-trip -> ONE barrier per step.
__global__ __launch_bounds__(128)
__attribute__((amdgpu_waves_per_eu(1, 1)))
void k_rnn1(
    const float* __restrict__ pre1, const float* __restrict__ Whh1,
    bf16_t* __restrict__ out1)
{
    __shared__ __align__(16) float hb[2][HID];      // double-buffered hidden state
    __shared__ __align__(16) float spre[CH * HID];  // staged pre rows (16 KB)
    __shared__ __align__(16) bf16_t sout[CH * HID]; // staged out rows (8 KB)
    const int b = blockIdx.x;
    const int i = threadIdx.x;
    const float4* wr = reinterpret_cast<const float4*>(Whh1 + i * HID);
    W32LOAD; W32PIN;
    hb[0][i] = 0.f;
    const float4* gsrc = reinterpret_cast<const float4*>(pre1 + (size_t)b * 512 * HID);
    uint4*        gdst = reinterpret_cast<uint4*>(out1 + (size_t)b * 512 * HID);
    float4*       spv  = reinterpret_cast<float4*>(spre);
    const uint4*  sov  = reinterpret_cast<const uint4*>(sout);
    for (int c = 0; c < 512 / CH; ++c) {
        // stage next CH pre rows: CH*HID/4 = 1024 float4, 8 per thread
        float4 r[8];
#pragma unroll
        for (int k = 0; k < 8; ++k) r[k] = gsrc[c * 1024 + i + k * 128];
        // flush previous chunk's outputs (LDS stable since last step barrier)
        if (c) {
            uint4 f[4];
#pragma unroll
            for (int k = 0; k < 4; ++k) f[k] = sov[i + k * 128];
#pragma unroll
            for (int k = 0; k < 4; ++k) gdst[(c - 1) * 512 + i + k * 128] = f[k];
        }
#pragma unroll
        for (int k = 0; k < 8; ++k) spv[i + k * 128] = r[k];
        __syncthreads();
        for (int s = 0; s < CH; ++s) {
            const int t = c * CH + s;
            const float4* hp = reinterpret_cast<const float4*>(hb[t & 1]);
            float a0 = spre[s * HID + i], a1 = 0, a2 = 0, a3 = 0;
            ACC32;
            float hn = fast_tanh((a0 + a1) + (a2 + a3));
            hb[(t + 1) & 1][i] = hn;    // other buffer: no WAR on current reads
            sout[s * HID + i] = f2bf(hn);
            __syncthreads();            // the ONLY barrier per step
        }
    }
    uint4 f[4];
#pragma unroll
    for (int k = 0; k < 4; ++k) f[k] = sov[i + k * 128];
#pragma unroll
    for (int k = 0; k < 4; ++k) gdst[15 * 512 + i + k * 128] = f[k];
}

// ---------------- kernel 3: layer-2 input GEMM (+both biases), 16 positions/block
__global__ __launch_bounds__(128)
__attribute__((amdgpu_waves_per_eu(1, 2)))
void k_pre2(
    const bf16_t* __restrict__ out1, const float* __restrict__ Wih2,
    const float* __restrict__ bih2, const float* __restrict__ bhh2,
    float* __restrict__ pre2)
{
    __shared__ __align__(16) float se[16 * HID];
    const int base = blockIdx.x * 16;
    const int i = threadIdx.x;
    const uint4* src = reinterpret_cast<const uint4*>(out1 + (size_t)base * HID);
#pragma unroll
    for (int k = 0; k < 2; ++k) {
        int idx = i + k * 128;
        uint4 u = src[idx];
        int e = idx * 8;
        se[e+0] = bf2f((bf16_t)(u.x & 0xffff)); se[e+1] = bf2f((bf16_t)(u.x >> 16));
        se[e+2] = bf2f((bf16_t)(u.y & 0xffff)); se[e+3] = bf2f((bf16_t)(u.y >> 16));
        se[e+4] = bf2f((bf16_t)(u.z & 0xffff)); se[e+5] = bf2f((bf16_t)(u.z >> 16));
        se[e+6] = bf2f((bf16_t)(u.w & 0xffff)); se[e+7] = bf2f((bf16_t)(u.w >> 16));
    }
    __syncthreads();
    const float4* wr = reinterpret_cast<const float4*>(Wih2 + i * HID);
    W32LOAD; W32PIN;
    const float bias = bih2[i] + bhh2[i];
    float* outp = pre2 + (size_t)base * HID + i;
#pragma unroll
    for (int p = 0; p < 16; ++p) {
        const float4* hp = reinterpret_cast<const float4*>(se + p * HID);
        float a0 = 0, a1 = 0, a2 = 0, a3 = 0;
        ACC32;
        outp[p * HID] = bias + ((a0 + a1) + (a2 + a3));
    }
}

// block-of-128 sum (2 waves)
__device__ inline float bsum128(float v, volatile float* sc, int tid) {
#pragma unroll
    for (int off = 32; off > 0; off >>= 1) v += __shfl_down(v, off, 64);
    __syncthreads();
    if ((tid & 63) == 0) sc[tid >> 6] = v;
    __syncthreads();
    return sc[0] + sc[1];
}

// ---------------- kernel 4: layer-2 recurrence + LN -> proj+tanh -> LN epilogue
__global__ __launch_bounds__(128)
__attribute__((amdgpu_waves_per_eu(1, 1)))
void k_rnn2_out(
    const float* __restrict__ pre2, const float* __restrict__ Whh2,
    const float* __restrict__ ln_g, const float* __restrict__ ln_b,
    const float* __restrict__ projW, const float* __restrict__ proj_b,
    const float* __restrict__ on_g, const float* __restrict__ on_b,
    float* __restrict__ out)
{
    __shared__ __align__(16) float hb[2][HID];
    __shared__ __align__(16) float spre[CH * HID];
    __shared__ float sc[2];
    const int b = blockIdx.x;
    const int i = threadIdx.x;
    float hn = 0.f;
    {
        const float4* wr = reinterpret_cast<const float4*>(Whh2 + i * HID);
        W32LOAD; W32PIN;
        hb[0][i] = 0.f;
        const float4* gsrc = reinterpret_cast<const float4*>(pre2 + (size_t)b * 512 * HID);
        float4*       spv  = reinterpret_cast<float4*>(spre);
        for (int c = 0; c < 512 / CH; ++c) {
            float4 r[8];
#pragma unroll
            for (int k = 0; k < 8; ++k) r[k] = gsrc[c * 1024 + i + k * 128];
#pragma unroll
            for (int k = 0; k < 8; ++k) spv[i + k * 128] = r[k];
            __syncthreads();
            for (int s = 0; s < CH; ++s) {
                const int t = c * CH + s;
                const float4* hp = reinterpret_cast<const float4*>(hb[t & 1]);
                float a0 = spre[s * HID + i], a1 = 0, a2 = 0, a3 = 0;
                ACC32;
                hn = fast_tanh((a0 + a1) + (a2 + a3));
                hb[(t + 1) & 1][i] = hn;
                __syncthreads();
            }
        }
    }
    // ---- layernorm 1
    float s1 = bsum128(hn, sc, i);
    float s2 = bsum128(hn * hn, sc, i);
    float mu = s1 * (1.f / 128.f);
    float var = s2 * (1.f / 128.f) - mu * mu;
    float rep = (hn - mu) * rsqrtf(var + 1e-5f) * ln_g[i] + ln_b[i];
    __syncthreads();
    hb[0][i] = rep;
    __syncthreads();
    // ---- proj + tanh (one-time, precise tanhf — off the critical path)
    float a0 = proj_b[i], a1 = 0, a2 = 0, a3 = 0;
    const float4* hp = reinterpret_cast<const float4*>(hb[0]);
    const float4* pr = reinterpret_cast<const float4*>(projW + i * HID);
#pragma unroll
    for (int c = 0; c < HID / 4; ++c) {
        float4 u = pr[c];
        float4 hv = hp[c];
        a0 = fmaf(hv.x, u.x, a0); a1 = fmaf(hv.y, u.y, a1);
        a2 = fmaf(hv.z, u.z, a2); a3 = fmaf(hv.w, u.w, a3);
    }
    float pv = tanhf((a0 + a1) + (a2 + a3));
    // ---- layernorm 2
    float t1 = bsum128(pv, sc, i);
    float t2 = bsum128(pv * pv, sc, i);
    float mu2 = t1 * (1.f / 128.f);
    float var2 = t2 * (1.f / 128.f) - mu2 * mu2;
    out[(size_t)b * HID + i] = (pv - mu2) * rsqrtf(var2 + 1e-5f) * on_g[i] + on_b[i];
}

extern "C" void kernel_launch(void* const* d_in, const int* in_sizes, int n_in,
                              void* d_out, int out_size, void* d_ws, size_t ws_size,
                              hipStream_t stream)
{
    const int*   x     = (const int*)  d_in[0];
    const float* emb   = (const float*)d_in[1];
    const float* Wih1  = (const float*)d_in[2];
    const float* bih1  = (const float*)d_in[3];
    const float* Whh1  = (const float*)d_in[4];
    const float* bhh1  = (const float*)d_in[5];
    const float* Wih2  = (const float*)d_in[6];
    const float* bih2  = (const float*)d_in[7];
    const float* Whh2  = (const float*)d_in[8];
    const float* bhh2  = (const float*)d_in[9];
    const float* ln_g  = (const float*)d_in[10];
    const float* ln_b  = (const float*)d_in[11];
    const float* projW = (const float*)d_in[12];
    const float* projb = (const float*)d_in[13];
    const float* on_g  = (const float*)d_in[14];
    const float* on_b  = (const float*)d_in[15];

    char* ws = (char*)d_ws;
    float*  pre  = (float*)ws;                               // 64 MiB fp32, reused by both layers
    bf16_t* out1 = (bf16_t*)(ws + (size_t)BT * HID * 4);     // 32 MiB bf16

    k_embed_pre1<<<BT / 8, 128, 0, stream>>>(x, emb, Wih1, bih1, bhh1, pre);
    k_rnn1<<<256, 128, 0, stream>>>(pre, Whh1, out1);
    k_pre2<<<BT / 16, 128, 0, stream>>>(out1, Wih2, bih2, bhh2, pre);
    k_rnn2_out<<<256, 128, 0, stream>>>(pre, Whh2, ln_g, ln_b, projW, projb,
                                        on_g, on_b, (float*)d_out);
}

// Round 10
// 716.724 us; speedup vs baseline: 1.1970x; 1.1970x over previous
//
#include <hip/hip_runtime.h>

#define BT (256*512)   // 131072 positions
#define HID 128
#define EMB 64
#define CH 32          // scan chunk: steps staged per LDS refill

typedef unsigned short bf16_t;

__device__ inline float bf2f(bf16_t u) {
    union { unsigned int i; float f; } v; v.i = ((unsigned int)u) << 16; return v.f;
}
__device__ inline bf16_t f2bf(float f) {
    union { float f; unsigned int i; } v; v.f = f;
    unsigned int x = v.i;
    return (bf16_t)((x + 0x7fffu + ((x >> 16) & 1u)) >> 16);  // RNE
}
// tanh(x) = 1 - 2/(exp(2x)+1)  — stable at both infinities, ~1e-6 abs error
__device__ inline float fast_tanh(float x) {
    float e = __expf(2.f * x);
    return 1.f - __fdividef(2.f, e + 1.f);
}

// pin a float4 in VGPRs (compiler cannot rematerialize past this)
#define OPQ(v) asm volatile("" : "+v"(v.x), "+v"(v.y), "+v"(v.z), "+v"(v.w))
#define W16LOAD \
    float4 w0=wr[0],w1=wr[1],w2=wr[2],w3=wr[3],w4=wr[4],w5=wr[5],w6=wr[6],w7=wr[7], \
           w8=wr[8],w9=wr[9],w10=wr[10],w11=wr[11],w12=wr[12],w13=wr[13],w14=wr[14],w15=wr[15];
#define W16PIN \
    OPQ(w0);OPQ(w1);OPQ(w2);OPQ(w3);OPQ(w4);OPQ(w5);OPQ(w6);OPQ(w7); \
    OPQ(w8);OPQ(w9);OPQ(w10);OPQ(w11);OPQ(w12);OPQ(w13);OPQ(w14);OPQ(w15);
#define ACC4(n) { float4 hv = hp[n]; \
    a0 = fmaf(hv.x, w##n.x, a0); a1 = fmaf(hv.y, w##n.y, a1); \
    a2 = fmaf(hv.z, w##n.z, a2); a3 = fmaf(hv.w, w##n.w, a3); }
#define ACC16 ACC4(0)ACC4(1)ACC4(2)ACC4(3)ACC4(4)ACC4(5)ACC4(6)ACC4(7) \
              ACC4(8)ACC4(9)ACC4(10)ACC4(11)ACC4(12)ACC4(13)ACC4(14)ACC4(15)

// ================= GEMM kernels: LDS-tiled fp32, 128pos x 128out / block ====
// sA[k][pos], sW[k][out] staged transposed per 32-wide K chunk; thread (tx,ty)
// computes an 8x8 register tile: per j, 4 ds_read_b128 + 64 v_fmac (VALU-bound).

// ---------------- kernel 1: embedding gather + layer-1 input GEMM (+biases)
__global__ __launch_bounds__(256) void k_embed_pre1(
    const int* __restrict__ x, const float* __restrict__ emb,
    const float* __restrict__ Wih1, const float* __restrict__ bih1,
    const float* __restrict__ bhh1, float* __restrict__ pre1)
{
    __shared__ float sA[32][128];
    __shared__ float sW[32][132];
    __shared__ int stok[128];
    const int tid = threadIdx.x;
    const int base = blockIdx.x * 128;
    const int tx = tid & 15, ty = tid >> 4;
    const int ox = tx * 8, py = ty * 8;
    const int pl = tid & 127, half = tid >> 7;
    if (tid < 128) stok[tid] = x[base + tid];
    float acc[8][8];
#pragma unroll
    for (int p = 0; p < 8; ++p)
#pragma unroll
        for (int o = 0; o < 8; ++o) acc[p][o] = 0.f;
    __syncthreads();
    for (int kc = 0; kc < 2; ++kc) {            // K = 64
        {
            const float4* ws = (const float4*)(Wih1 + (size_t)pl * EMB + kc * 32 + half * 16);
            float4 q0 = ws[0], q1 = ws[1], q2 = ws[2], q3 = ws[3];
            const float4* as = (const float4*)(emb + (size_t)stok[pl] * EMB + kc * 32 + half * 16);
            float4 e0 = as[0], e1 = as[1], e2 = as[2], e3 = as[3];
            const int jb = half * 16;
            sW[jb+ 0][pl]=q0.x; sW[jb+ 1][pl]=q0.y; sW[jb+ 2][pl]=q0.z; sW[jb+ 3][pl]=q0.w;
            sW[jb+ 4][pl]=q1.x; sW[jb+ 5][pl]=q1.y; sW[jb+ 6][pl]=q1.z; sW[jb+ 7][pl]=q1.w;
            sW[jb+ 8][pl]=q2.x; sW[jb+ 9][pl]=q2.y; sW[jb+10][pl]=q2.z; sW[jb+11][pl]=q2.w;
            sW[jb+12][pl]=q3.x; sW[jb+13][pl]=q3.y; sW[jb+14][pl]=q3.z; sW[jb+15][pl]=q3.w;
            sA[jb+ 0][pl]=e0.x; sA[jb+ 1][pl]=e0.y; sA[jb+ 2][pl]=e0.z; sA[jb+ 3][pl]=e0.w;
            sA[jb+ 4][pl]=e1.x; sA[jb+ 5][pl]=e1.y; sA[jb+ 6][pl]=e1.z; sA[jb+ 7][pl]=e1.w;
            sA[jb+ 8][pl]=e2.x; sA[jb+ 9][pl]=e2.y; sA[jb+10][pl]=e2.z; sA[jb+11][pl]=e2.w;
            sA[jb+12][pl]=e3.x; sA[jb+13][pl]=e3.y; sA[jb+14][pl]=e3.z; sA[jb+15][pl]=e3.w;
        }
        __syncthreads();
#pragma unroll 4
        for (int j = 0; j < 32; ++j) {
            float4 a0 = *(const float4*)&sA[j][py];
            float4 a1 = *(const float4*)&sA[j][py + 4];
            float4 b0 = *(const float4*)&sW[j][ox];
            float4 b1 = *(const float4*)&sW[j][ox + 4];
            float av[8] = {a0.x,a0.y,a0.z,a0.w,a1.x,a1.y,a1.z,a1.w};
            float bv[8] = {b0.x,b0.y,b0.z,b0.w,b1.x,b1.y,b1.z,b1.w};
#pragma unroll
            for (int p = 0; p < 8; ++p)
#pragma unroll
                for (int o = 0; o < 8; ++o)
                    acc[p][o] = fmaf(av[p], bv[o], acc[p][o]);
        }
        __syncthreads();
    }
    float bo[8];
#pragma unroll
    for (int o = 0; o < 8; ++o) bo[o] = bih1[ox + o] + bhh1[ox + o];
#pragma unroll
    for (int p = 0; p < 8; ++p) {
        float* cp = pre1 + (size_t)(base + py + p) * HID + ox;
        *(float4*)cp       = make_float4(acc[p][0]+bo[0], acc[p][1]+bo[1], acc[p][2]+bo[2], acc[p][3]+bo[3]);
        *(float4*)(cp + 4) = make_float4(acc[p][4]+bo[4], acc[p][5]+bo[5], acc[p][6]+bo[6], acc[p][7]+bo[7]);
    }
}

// ---------------- kernel 3: layer-2 input GEMM (+biases), A = bf16 out1
__global__ __launch_bounds__(256) void k_pre2(
    const bf16_t* __restrict__ out1, const float* __restrict__ Wih2,
    const float* __restrict__ bih2, const float* __restrict__ bhh2,
    float* __restrict__ pre2)
{
    __shared__ float sA[32][128];
    __shared__ float sW[32][132];
    const int tid = threadIdx.x;
    const int base = blockIdx.x * 128;
    const int tx = tid & 15, ty = tid >> 4;
    const int ox = tx * 8, py = ty * 8;
    const int pl = tid & 127, half = tid >> 7;
    float acc[8][8];
#pragma unroll
    for (int p = 0; p < 8; ++p)
#pragma unroll
        for (int o = 0; o < 8; ++o) acc[p][o] = 0.f;
    for (int kc = 0; kc < 4; ++kc) {            // K = 128
        {
            const float4* ws = (const float4*)(Wih2 + (size_t)pl * HID + kc * 32 + half * 16);
            float4 q0 = ws[0], q1 = ws[1], q2 = ws[2], q3 = ws[3];
            const uint4* as = (const uint4*)(out1 + (size_t)(base + pl) * HID + kc * 32 + half * 16);
            uint4 u0 = as[0], u1 = as[1];
            const int jb = half * 16;
            sW[jb+ 0][pl]=q0.x; sW[jb+ 1][pl]=q0.y; sW[jb+ 2][pl]=q0.z; sW[jb+ 3][pl]=q0.w;
            sW[jb+ 4][pl]=q1.x; sW[jb+ 5][pl]=q1.y; sW[jb+ 6][pl]=q1.z; sW[jb+ 7][pl]=q1.w;
            sW[jb+ 8][pl]=q2.x; sW[jb+ 9][pl]=q2.y; sW[jb+10][pl]=q2.z; sW[jb+11][pl]=q2.w;
            sW[jb+12][pl]=q3.x; sW[jb+13][pl]=q3.y; sW[jb+14][pl]=q3.z; sW[jb+15][pl]=q3.w;
            sA[jb+ 0][pl]=bf2f((bf16_t)(u0.x & 0xffff)); sA[jb+ 1][pl]=bf2f((bf16_t)(u0.x >> 16));
            sA[jb+ 2][pl]=bf2f((bf16_t)(u0.y & 0xffff)); sA[jb+ 3][pl]=bf2f((bf16_t)(u0.y >> 16));
            sA[jb+ 4][pl]=bf2f((bf16_t)(u0.z & 0xffff)); sA[jb+ 5][pl]=bf2f((bf16_t)(u0.z >> 16));
            sA[jb+ 6][pl]=bf2f((bf16_t)(u0.w & 0xffff)); sA[jb+ 7][pl]=bf2f((bf16_t)(u0.w >> 16));
            sA[jb+ 8][pl]=bf2f((bf16_t)(u1.x & 0xffff)); sA[jb+ 9][pl]=bf2f((bf16_t)(u1.x >> 16));
            sA[jb+10][pl]=bf2f((bf16_t)(u1.y & 0xffff)); sA[jb+11][pl]=bf2f((bf16_t)(u1.y >> 16));
            sA[jb+12][pl]=bf2f((bf16_t)(u1.z & 0xffff)); sA[jb+13][pl]=bf2f((bf16_t)(u1.z >> 16));
            sA[jb+14][pl]=bf2f((bf16_t)(u1.w & 0xffff)); sA[jb+15][pl]=bf2f((bf16_t)(u1.w >> 16));
        }
        __syncthreads();
#pragma unroll 4
        for (int j = 0; j < 32; ++j) {
            float4 a0 = *(const float4*)&sA[j][py];
            float4 a1 = *(const float4*)&sA[j][py + 4];
            float4 b0 = *(const float4*)&sW[j][ox];
            float4 b1 = *(const float4*)&sW[j][ox + 4];
            float av[8] = {a0.x,a0.y,a0.z,a0.w,a1.x,a1.y,a1.z,a1.w};
            float bv[8] = {b0.x,b0.y,b0.z,b0.w,b1.x,b1.y,b1.z,b1.w};
#pragma unroll
            for (int p = 0; p < 8; ++p)
#pragma unroll
                for (int o = 0; o < 8; ++o)
                    acc[p][o] = fmaf(av[p], bv[o], acc[p][o]);
        }
        __syncthreads();
    }
    float bo[8];
#pragma unroll
    for (int o = 0; o < 8; ++o) bo[o] = bih2[ox + o] + bhh2[ox + o];
#pragma unroll
    for (int p = 0; p < 8; ++p) {
        float* cp = pre2 + (size_t)(base + py + p) * HID + ox;
        *(float4*)cp       = make_float4(acc[p][0]+bo[0], acc[p][1]+bo[1], acc[p][2]+bo[2], acc[p][3]+bo[3]);
        *(float4*)(cp + 4) = make_float4(acc[p][4]+bo[4], acc[p][5]+bo[5], acc[p][6]+bo[6], acc[p][7]+bo[7]);
    }
}

// ================= scan kernels: R7 verbatim (fp32 weights — R9 lesson) =====

// ---------------- kernel 2: layer-1 recurrence. one block per batch row,
// 256 threads, 2-way K-split, 64 pinned weight floats/thread (VGPR=132, R6).
__global__ __launch_bounds__(256)
__attribute__((amdgpu_waves_per_eu(1, 1)))
void k_rnn1(
    const float* __restrict__ pre1, const float* __restrict__ Whh1,
    bf16_t* __restrict__ out1)
{
    __shared__ __align__(16) float hb[2][HID];
    __shared__ __align__(16) float sp[2][HID];
    __shared__ __align__(16) float spre[CH * HID];
    __shared__ __align__(16) bf16_t sout[CH * HID];
    const int b    = blockIdx.x;
    const int tid  = threadIdx.x;
    const int i    = tid & 127;
    const int half = tid >> 7;
    const float4* wr = reinterpret_cast<const float4*>(Whh1 + i * HID + half * 64);
    W16LOAD; W16PIN;
    if (tid < 128) hb[0][i] = 0.f;
    const float4* gsrc = reinterpret_cast<const float4*>(pre1 + (size_t)b * 512 * HID);
    uint4*        gdst = reinterpret_cast<uint4*>(out1 + (size_t)b * 512 * HID);
    float4*       spv  = reinterpret_cast<float4*>(spre);
    const uint4*  sov  = reinterpret_cast<const uint4*>(sout);
    for (int c = 0; c < 512 / CH; ++c) {
        float4 r0 = gsrc[c * 1024 + tid];
        float4 r1 = gsrc[c * 1024 + tid + 256];
        float4 r2 = gsrc[c * 1024 + tid + 512];
        float4 r3 = gsrc[c * 1024 + tid + 768];
        if (c) {
            uint4 f0 = sov[tid], f1 = sov[tid + 256];
            gdst[(c - 1) * 512 + tid]       = f0;
            gdst[(c - 1) * 512 + tid + 256] = f1;
        }
        spv[tid]       = r0;
        spv[tid + 256] = r1;
        spv[tid + 512] = r2;
        spv[tid + 768] = r3;
        __syncthreads();
        for (int s = 0; s < CH; ++s) {
            const int t = c * CH + s;
            const float4* hp = reinterpret_cast<const float4*>(hb[t & 1] + half * 64);
            float a0 = 0, a1 = 0, a2 = 0, a3 = 0;
            ACC16;
            sp[half][i] = (a0 + a1) + (a2 + a3);
            __syncthreads();
            if (tid < 128) {
                float hn = fast_tanh(spre[s * HID + i] + sp[0][i] + sp[1][i]);
                hb[(t + 1) & 1][i] = hn;
                sout[s * HID + i] = f2bf(hn);
            }
            __syncthreads();
        }
    }
    uint4 f0 = sov[tid], f1 = sov[tid + 256];
    gdst[15 * 512 + tid]       = f0;
    gdst[15 * 512 + tid + 256] = f1;
}

// block-wide sum over the 128 values held by tid<128 (all 256 threads call;
// half-1 threads must pass v=0). Unconditional barriers.
__device__ inline float bsum_all(float v, volatile float* sc, int tid) {
#pragma unroll
    for (int off = 32; off > 0; off >>= 1) v += __shfl_down(v, off, 64);
    __syncthreads();
    if (tid < 128 && (tid & 63) == 0) sc[tid >> 6] = v;
    __syncthreads();
    return sc[0] + sc[1];
}

// ---------------- kernel 4: layer-2 recurrence + LN -> proj+tanh -> LN
__global__ __launch_bounds__(256)
__attribute__((amdgpu_waves_per_eu(1, 1)))
void k_rnn2_out(
    const float* __restrict__ pre2, const float* __restrict__ Whh2,
    const float* __restrict__ ln_g, const float* __restrict__ ln_b,
    const float* __restrict__ projW, const float* __restrict__ proj_b,
    const float* __restrict__ on_g, const float* __restrict__ on_b,
    float* __restrict__ out)
{
    __shared__ __align__(16) float hb[2][HID];
    __shared__ __align__(16) float sp[2][HID];
    __shared__ __align__(16) float spre[CH * HID];
    __shared__ float sc[2];
    const int b    = blockIdx.x;
    const int tid  = threadIdx.x;
    const int i    = tid & 127;
    const int half = tid >> 7;
    const float4* wr = reinterpret_cast<const float4*>(Whh2 + i * HID + half * 64);
    W16LOAD; W16PIN;
    if (tid < 128) hb[0][i] = 0.f;
    const float4* gsrc = reinterpret_cast<const float4*>(pre2 + (size_t)b * 512 * HID);
    float4*       spv  = reinterpret_cast<float4*>(spre);
    float hn = 0.f;
    for (int c = 0; c < 512 / CH; ++c) {
        float4 r0 = gsrc[c * 1024 + tid];
        float4 r1 = gsrc[c * 1024 + tid + 256];
        float4 r2 = gsrc[c * 1024 + tid + 512];
        float4 r3 = gsrc[c * 1024 + tid + 768];
        spv[tid]       = r0;
        spv[tid + 256] = r1;
        spv[tid + 512] = r2;
        spv[tid + 768] = r3;
        __syncthreads();
        for (int s = 0; s < CH; ++s) {
            const int t = c * CH + s;
            const float4* hp = reinterpret_cast<const float4*>(hb[t & 1] + half * 64);
            float a0 = 0, a1 = 0, a2 = 0, a3 = 0;
            ACC16;
            sp[half][i] = (a0 + a1) + (a2 + a3);
            __syncthreads();
            if (tid < 128) {
                hn = fast_tanh(spre[s * HID + i] + sp[0][i] + sp[1][i]);
                hb[(t + 1) & 1][i] = hn;
            }
            __syncthreads();
        }
    }
    float s1 = bsum_all(tid < 128 ? hn : 0.f, sc, tid);
    float s2 = bsum_all(tid < 128 ? hn * hn : 0.f, sc, tid);
    float mu = s1 * (1.f / 128.f);
    float var = s2 * (1.f / 128.f) - mu * mu;
    __syncthreads();
    if (tid < 128) hb[0][i] = (hn - mu) * rsqrtf(var + 1e-5f) * ln_g[i] + ln_b[i];
    __syncthreads();
    float pv = 0.f;
    if (tid < 128) {
        float a0 = proj_b[i], a1 = 0, a2 = 0, a3 = 0;
        const float4* hp = reinterpret_cast<const float4*>(hb[0]);
        const float4* pr = reinterpret_cast<const float4*>(projW + i * HID);
#pragma unroll
        for (int c = 0; c < HID / 4; ++c) {
            float4 u = pr[c];
            float4 hv = hp[c];
            a0 = fmaf(hv.x, u.x, a0); a1 = fmaf(hv.y, u.y, a1);
            a2 = fmaf(hv.z, u.z, a2); a3 = fmaf(hv.w, u.w, a3);
        }
        pv = tanhf((a0 + a1) + (a2 + a3));
    }
    float t1 = bsum_all(pv, sc, tid);
    float t2 = bsum_all(pv * pv, sc, tid);
    float mu2 = t1 * (1.f / 128.f);
    float var2 = t2 * (1.f / 128.f) - mu2 * mu2;
    if (tid < 128)
        out[(size_t)b * HID + i] = (pv - mu2) * rsqrtf(var2 + 1e-5f) * on_g[i] + on_b[i];
}

extern "C" void kernel_launch(void* const* d_in, const int* in_sizes, int n_in,
                              void* d_out, int out_size, void* d_ws, size_t ws_size,
                              hipStream_t stream)
{
    const int*   x     = (const int*)  d_in[0];
    const float* emb   = (const float*)d_in[1];
    const float* Wih1  = (const float*)d_in[2];
    const float* bih1  = (const float*)d_in[3];
    const float* Whh1  = (const float*)d_in[4];
    const float* bhh1  = (const float*)d_in[5];
    const float* Wih2  = (const float*)d_in[6];
    const float* bih2  = (const float*)d_in[7];
    const float* Whh2  = (const float*)d_in[8];
    const float* bhh2  = (const float*)d_in[9];
    const float* ln_g  = (const float*)d_in[10];
    const float* ln_b  = (const float*)d_in[11];
    const float* projW = (const float*)d_in[12];
    const float* projb = (const float*)d_in[13];
    const float* on_g  = (const float*)d_in[14];
    const float* on_b  = (const float*)d_in[15];

    char* ws = (char*)d_ws;
    float*  pre  = (float*)ws;                               // 64 MiB fp32, reused by both layers
    bf16_t* out1 = (bf16_t*)(ws + (size_t)BT * HID * 4);     // 32 MiB bf16

    k_embed_pre1<<<BT / 128, 256, 0, stream>>>(x, emb, Wih1, bih1, bhh1, pre);
    k_rnn1<<<256, 256, 0, stream>>>(pre, Whh1, out1);
    k_pre2<<<BT / 128, 256, 0, stream>>>(out1, Wih2, bih2, bhh2, pre);
    k_rnn2_out<<<256, 256, 0, stream>>>(pre, Whh2, ln_g, ln_b, projW, projb,
                                        on_g, on_b, (float*)d_out);
}

// Round 12
// 568.345 us; speedup vs baseline: 1.5096x; 1.2611x over previous
//
#include <hip/hip_runtime.h>

#define BT (256*512)   // 131072 positions
#define HID 128
#define EMB 64
#define CH 32          // scan chunk: steps staged per LDS refill

typedef _Float16 half2_t __attribute__((ext_vector_type(2)));

__device__ inline float fast_tanh(float x) {   // 1 - 2/(exp(2x)+1), ~1e-6 abs err
    float e = __expf(2.f * x);
    return 1.f - __fdividef(2.f, e + 1.f);
}

// pin a float4 in VGPRs (compiler cannot rematerialize past this) — R6 recipe
#define OPQ(v) asm volatile("" : "+v"(v.x), "+v"(v.y), "+v"(v.z), "+v"(v.w))
#define W16LOAD \
    float4 w0=wr[0],w1=wr[1],w2=wr[2],w3=wr[3],w4=wr[4],w5=wr[5],w6=wr[6],w7=wr[7], \
           w8=wr[8],w9=wr[9],w10=wr[10],w11=wr[11],w12=wr[12],w13=wr[13],w14=wr[14],w15=wr[15];
#define W16PIN \
    OPQ(w0);OPQ(w1);OPQ(w2);OPQ(w3);OPQ(w4);OPQ(w5);OPQ(w6);OPQ(w7); \
    OPQ(w8);OPQ(w9);OPQ(w10);OPQ(w11);OPQ(w12);OPQ(w13);OPQ(w14);OPQ(w15);

// fp32 dot: 16 float4 h reads × pinned weight float4s
#define ACC4(n) { float4 hv = hp[n]; \
    a0 = fmaf(hv.x, w##n.x, a0); a1 = fmaf(hv.y, w##n.y, a1); \
    a2 = fmaf(hv.z, w##n.z, a2); a3 = fmaf(hv.w, w##n.w, a3); }
#define ACC16 ACC4(0)ACC4(1)ACC4(2)ACC4(3)ACC4(4)ACC4(5)ACC4(6)ACC4(7) \
              ACC4(8)ACC4(9)ACC4(10)ACC4(11)ACC4(12)ACC4(13)ACC4(14)ACC4(15)

// fp16-pair h × fp32 weights: one uint4 = 8 h values (layer-2 input path only)
#define BCH(u) __builtin_bit_cast(half2_t, u)
#define FMX(q, wa, wb) { \
    half2_t p0=BCH(q.x), p1=BCH(q.y), p2=BCH(q.z), p3=BCH(q.w); \
    a0 = fmaf((float)p0.x, wa.x, a0); a1 = fmaf((float)p0.y, wa.y, a1); \
    a2 = fmaf((float)p1.x, wa.z, a2); a3 = fmaf((float)p1.y, wa.w, a3); \
    a0 = fmaf((float)p2.x, wb.x, a0); a1 = fmaf((float)p2.y, wb.y, a1); \
    a2 = fmaf((float)p3.x, wb.z, a2); a3 = fmaf((float)p3.y, wb.w, a3); }
#define DOT64H(hsrc) \
    uint4 q0=hsrc[0],q1=hsrc[1],q2=hsrc[2],q3=hsrc[3], \
          q4=hsrc[4],q5=hsrc[5],q6=hsrc[6],q7=hsrc[7]; \
    FMX(q0,w0,w1) FMX(q1,w2,w3) FMX(q2,w4,w5) FMX(q3,w6,w7) \
    FMX(q4,w8,w9) FMX(q5,w10,w11) FMX(q6,w12,w13) FMX(q7,w14,w15)

// ---------------- kernel 1: embedding gather + layer-1 input GEMM (R10 form)
__global__ __launch_bounds__(256) void k_embed_pre1(
    const int* __restrict__ x, const float* __restrict__ emb,
    const float* __restrict__ Wih1, const float* __restrict__ bih1,
    const float* __restrict__ bhh1, float* __restrict__ pre1)
{
    __shared__ float sA[32][128];
    __shared__ float sW[32][132];
    __shared__ int stok[128];
    const int tid = threadIdx.x;
    const int base = blockIdx.x * 128;
    const int tx = tid & 15, ty = tid >> 4;
    const int ox = tx * 8, py = ty * 8;
    const int pl = tid & 127, half = tid >> 7;
    if (tid < 128) stok[tid] = x[base + tid];
    float acc[8][8];
#pragma unroll
    for (int p = 0; p < 8; ++p)
#pragma unroll
        for (int o = 0; o < 8; ++o) acc[p][o] = 0.f;
    __syncthreads();
    for (int kc = 0; kc < 2; ++kc) {            // K = 64
        {
            const float4* ws = (const float4*)(Wih1 + (size_t)pl * EMB + kc * 32 + half * 16);
            float4 q0 = ws[0], q1 = ws[1], q2 = ws[2], q3 = ws[3];
            const float4* as = (const float4*)(emb + (size_t)stok[pl] * EMB + kc * 32 + half * 16);
            float4 e0 = as[0], e1 = as[1], e2 = as[2], e3 = as[3];
            const int jb = half * 16;
            sW[jb+ 0][pl]=q0.x; sW[jb+ 1][pl]=q0.y; sW[jb+ 2][pl]=q0.z; sW[jb+ 3][pl]=q0.w;
            sW[jb+ 4][pl]=q1.x; sW[jb+ 5][pl]=q1.y; sW[jb+ 6][pl]=q1.z; sW[jb+ 7][pl]=q1.w;
            sW[jb+ 8][pl]=q2.x; sW[jb+ 9][pl]=q2.y; sW[jb+10][pl]=q2.z; sW[jb+11][pl]=q2.w;
            sW[jb+12][pl]=q3.x; sW[jb+13][pl]=q3.y; sW[jb+14][pl]=q3.z; sW[jb+15][pl]=q3.w;
            sA[jb+ 0][pl]=e0.x; sA[jb+ 1][pl]=e0.y; sA[jb+ 2][pl]=e0.z; sA[jb+ 3][pl]=e0.w;
            sA[jb+ 4][pl]=e1.x; sA[jb+ 5][pl]=e1.y; sA[jb+ 6][pl]=e1.z; sA[jb+ 7][pl]=e1.w;
            sA[jb+ 8][pl]=e2.x; sA[jb+ 9][pl]=e2.y; sA[jb+10][pl]=e2.z; sA[jb+11][pl]=e2.w;
            sA[jb+12][pl]=e3.x; sA[jb+13][pl]=e3.y; sA[jb+14][pl]=e3.z; sA[jb+15][pl]=e3.w;
        }
        __syncthreads();
#pragma unroll 4
        for (int j = 0; j < 32; ++j) {
            float4 a0 = *(const float4*)&sA[j][py];
            float4 a1 = *(const float4*)&sA[j][py + 4];
            float4 b0 = *(const float4*)&sW[j][ox];
            float4 b1 = *(const float4*)&sW[j][ox + 4];
            float av[8] = {a0.x,a0.y,a0.z,a0.w,a1.x,a1.y,a1.z,a1.w};
            float bv[8] = {b0.x,b0.y,b0.z,b0.w,b1.x,b1.y,b1.z,b1.w};
#pragma unroll
            for (int p = 0; p < 8; ++p)
#pragma unroll
                for (int o = 0; o < 8; ++o)
                    acc[p][o] = fmaf(av[p], bv[o], acc[p][o]);
        }
        __syncthreads();
    }
    float bo[8];
#pragma unroll
    for (int o = 0; o < 8; ++o) bo[o] = bih1[ox + o] + bhh1[ox + o];
#pragma unroll
    for (int p = 0; p < 8; ++p) {
        float* cp = pre1 + (size_t)(base + py + p) * HID + ox;
        *(float4*)cp       = make_float4(acc[p][0]+bo[0], acc[p][1]+bo[1], acc[p][2]+bo[2], acc[p][3]+bo[3]);
        *(float4*)(cp + 4) = make_float4(acc[p][4]+bo[4], acc[p][5]+bo[5], acc[p][6]+bo[6], acc[p][7]+bo[7]);
    }
}

// block-wide sum for 768 threads (12 waves); pass 0 from non-contributing lanes
__device__ inline float bsum768(float v, volatile float* sc, int tid) {
#pragma unroll
    for (int off = 32; off > 0; off >>= 1) v += __shfl_down(v, off, 64);
    __syncthreads();
    if ((tid & 63) == 0) sc[tid >> 6] = v;
    __syncthreads();
    float s = 0.f;
#pragma unroll
    for (int k = 0; k < 12; ++k) s += sc[k];
    return s;
}

// ---------------- kernel 2: FUSED two-layer recurrence + LN/proj/LN epilogue.
// One block (768 thr, 12 waves) per sequence, 1-step skew:
//   group A (waves 0-3):  Whh1 @ h1_{t-1}  (fp32 h)  -> h1_t
//   group B (waves 4-7):  Wih2 @ h1_{t-1}  (fp16 h — NON-recurrent path)
//   group C (waves 8-11): Whh2 @ h2_{t-2}  (fp32 h)  -> h2_{t-1} (with B's part)
// R9/R11 lesson: quantization INSIDE a recurrence amplifies ~100x over 512
// steps; feed-forward quantization is benign (R10). So recurrent h reads stay
// fp32; only B's input copy is fp16.
__global__ __launch_bounds__(768)
__attribute__((amdgpu_waves_per_eu(1, 3)))
void k_rnn_fused(
    const float* __restrict__ pre1, const float* __restrict__ Whh1,
    const float* __restrict__ Wih2, const float* __restrict__ bih2,
    const float* __restrict__ bhh2, const float* __restrict__ Whh2,
    const float* __restrict__ ln_g, const float* __restrict__ ln_b,
    const float* __restrict__ projW, const float* __restrict__ proj_b,
    const float* __restrict__ on_g, const float* __restrict__ on_b,
    float* __restrict__ out)
{
    __shared__ __align__(16) float    h1b[2][HID];   // fp32 h1 (recurrent read, A)
    __shared__ __align__(16) _Float16 h1h[2][HID];   // fp16 h1 copy (B only)
    __shared__ __align__(16) float    h2b[2][HID];   // fp32 h2 (recurrent read, C)
    __shared__ __align__(16) float sp[3][2][HID];    // per-group K-split partials
    __shared__ __align__(16) float spre[CH * HID];   // staged pre1 rows (16 KB)
    __shared__ float sfin[HID];
    __shared__ float sc[12];
    const int b    = blockIdx.x;
    const int tid  = threadIdx.x;
    const int g    = tid >> 8;        // 0=A,1=B,2=C (wave-uniform)
    const int gt   = tid & 255;
    const int i    = gt & 127;
    const int half = gt >> 7;
    const float* wbase = (g == 0) ? Whh1 : ((g == 1) ? Wih2 : Whh2);
    const float4* wr = reinterpret_cast<const float4*>(wbase + (size_t)i * HID + half * 64);
    W16LOAD; W16PIN;
    const float bias2 = (g == 1) ? (bih2[i] + bhh2[i]) : 0.f;
    if (tid < 128) {
        h1b[0][tid] = 0.f; h1h[0][tid] = (_Float16)0.f; h2b[0][tid] = 0.f;
    }
    const float4* gsrc = reinterpret_cast<const float4*>(pre1 + (size_t)b * 512 * HID);
    float4*       spv  = reinterpret_cast<float4*>(spre);
    __syncthreads();
    for (int c = 0; c < 512 / CH; ++c) {
        // stage CH pre1 rows: 1024 float4, threads 0..511 take 2 each
        if (tid < 512) {
            float4 r0 = gsrc[c * 1024 + tid];
            float4 r1 = gsrc[c * 1024 + tid + 512];
            spv[tid]       = r0;
            spv[tid + 512] = r1;
        }
        __syncthreads();
        for (int s = 0; s < CH; ++s) {
            const int t = c * CH + s;
            if (g == 1) {               // fp16 h1 read (feed-forward path)
                const uint4* hsrc = reinterpret_cast<const uint4*>(h1h[t & 1] + half * 64);
                float a0 = 0, a1 = 0, a2 = 0, a3 = 0;
                DOT64H(hsrc);
                sp[1][half][i] = (a0 + a1) + (a2 + a3);
            } else {                    // fp32 recurrent reads
                const float* hsel = (g == 0) ? h1b[t & 1] : h2b[t & 1];
                const float4* hp = reinterpret_cast<const float4*>(hsel + half * 64);
                float a0 = 0, a1 = 0, a2 = 0, a3 = 0;
                ACC16;
                sp[g][half][i] = (a0 + a1) + (a2 + a3);
            }
            __syncthreads();
            if (tid < 128) {               // waves 0-1: publish h1_t (both formats)
                float hn = fast_tanh(spre[s * HID + i] + sp[0][0][i] + sp[0][1][i]);
                h1b[(t + 1) & 1][i] = hn;
                h1h[(t + 1) & 1][i] = (_Float16)hn;
            } else if (g == 1 && gt < 128) {  // waves 4-5: publish h2_{t-1}
                float v = bias2 + sp[1][0][i] + sp[1][1][i] + sp[2][0][i] + sp[2][1][i];
                h2b[(t + 1) & 1][i] = (t > 0) ? fast_tanh(v) : 0.f;
            }
            __syncthreads();
        }
    }
    // drain: h2_511 = tanh(bias2 + Wih2@h1_511 + Whh2@h2_510)
    if (g == 1) {
        const uint4* hsrc = reinterpret_cast<const uint4*>(h1h[0] + half * 64);
        float a0 = 0, a1 = 0, a2 = 0, a3 = 0;
        DOT64H(hsrc);
        sp[1][half][i] = (a0 + a1) + (a2 + a3);
    } else if (g == 2) {
        const float4* hp = reinterpret_cast<const float4*>(h2b[0] + half * 64);
        float a0 = 0, a1 = 0, a2 = 0, a3 = 0;
        ACC16;
        sp[2][half][i] = (a0 + a1) + (a2 + a3);
    }
    __syncthreads();
    if (g == 1 && gt < 128)
        sfin[i] = fast_tanh(bias2 + sp[1][0][i] + sp[1][1][i] + sp[2][0][i] + sp[2][1][i]);
    __syncthreads();
    // ---- epilogue: LN -> proj+tanh -> LN (values on tid<128; all barrier)
    float hn = (tid < 128) ? sfin[i] : 0.f;
    float s1 = bsum768(hn, sc, tid);
    float s2 = bsum768(hn * hn, sc, tid);
    float mu = s1 * (1.f / 128.f);
    float var = s2 * (1.f / 128.f) - mu * mu;
    __syncthreads();
    if (tid < 128) spre[i] = (hn - mu) * rsqrtf(var + 1e-5f) * ln_g[i] + ln_b[i];
    __syncthreads();
    float pv = 0.f;
    if (tid < 128) {
        float a0 = proj_b[i], a1 = 0, a2 = 0, a3 = 0;
        const float4* hp = reinterpret_cast<const float4*>(spre);
        const float4* pr = reinterpret_cast<const float4*>(projW + (size_t)i * HID);
#pragma unroll
        for (int k = 0; k < HID / 4; ++k) {
            float4 u = pr[k];
            float4 hv = hp[k];
            a0 = fmaf(hv.x, u.x, a0); a1 = fmaf(hv.y, u.y, a1);
            a2 = fmaf(hv.z, u.z, a2); a3 = fmaf(hv.w, u.w, a3);
        }
        pv = tanhf((a0 + a1) + (a2 + a3));
    }
    float t1 = bsum768(pv, sc, tid);
    float t2 = bsum768(pv * pv, sc, tid);
    float mu2 = t1 * (1.f / 128.f);
    float var2 = t2 * (1.f / 128.f) - mu2 * mu2;
    if (tid < 128)
        out[(size_t)b * HID + i] = (pv - mu2) * rsqrtf(var2 + 1e-5f) * on_g[i] + on_b[i];
}

extern "C" void kernel_launch(void* const* d_in, const int* in_sizes, int n_in,
                              void* d_out, int out_size, void* d_ws, size_t ws_size,
                              hipStream_t stream)
{
    const int*   x     = (const int*)  d_in[0];
    const float* emb   = (const float*)d_in[1];
    const float* Wih1  = (const float*)d_in[2];
    const float* bih1  = (const float*)d_in[3];
    const float* Whh1  = (const float*)d_in[4];
    const float* bhh1  = (const float*)d_in[5];
    const float* Wih2  = (const float*)d_in[6];
    const float* bih2  = (const float*)d_in[7];
    const float* Whh2  = (const float*)d_in[8];
    const float* bhh2  = (const float*)d_in[9];
    const float* ln_g  = (const float*)d_in[10];
    const float* ln_b  = (const float*)d_in[11];
    const float* projW = (const float*)d_in[12];
    const float* projb = (const float*)d_in[13];
    const float* on_g  = (const float*)d_in[14];
    const float* on_b  = (const float*)d_in[15];

    float* pre1 = (float*)d_ws;   // 64 MiB fp32

    k_embed_pre1<<<BT / 128, 256, 0, stream>>>(x, emb, Wih1, bih1, bhh1, pre1);
    k_rnn_fused<<<256, 768, 0, stream>>>(pre1, Whh1, Wih2, bih2, bhh2, Whh2,
                                         ln_g, ln_b, projW, projb, on_g, on_b,
                                         (float*)d_out);
}